// Round 15
// baseline (171.217 us; speedup 1.0000x reference)
//
#include <hip/hip_runtime.h>
#include <hip/hip_cooperative_groups.h>
#include <hip/hip_bf16.h>
#include <math.h>

namespace cg = cooperative_groups;

#define B_N 2048
#define V_N 5023
#define V3_N 15069
#define NSJB 157
#define CHUNK 32

typedef float f32x4 __attribute__((ext_vector_type(4)));
typedef short short8 __attribute__((ext_vector_type(8)));

static __device__ __forceinline__ ushort f2bf(float f) {
  __hip_bfloat16 h = __float2bfloat16(f);
  return *reinterpret_cast<ushort*>(&h);
}

// ---------------- phase units (shared by coop + fallback kernels) ----------------

static __device__ __forceinline__ void basis_unit(int bx, int t,
                                                  const float* __restrict__ sdirs,
                                                  const float* __restrict__ pdirs,
                                                  ushort* __restrict__ basis) {
  __shared__ float Sh[16][452];
  __shared__ float Pd[36][48];
  int v0 = bx * 16;
  for (int idx = t; idx < 16 * 450; idx += 256) {
    int r = idx / 450, c = idx - r * 450;
    int v = v0 + r;
    Sh[r][c] = (v < V_N) ? sdirs[(size_t)v * 450 + c] : 0.0f;
  }
  for (int idx = t; idx < 36 * 48; idx += 256) {
    int p = idx / 48, c = idx - p * 48;
    int v3 = v0 * 3 + c;
    Pd[p][c] = (v3 < V3_N) ? pdirs[(size_t)p * V3_N + v3] : 0.0f;
  }
  __syncthreads();
  for (int idx = t; idx < 64 * 96; idx += 256) {
    int row = idx / 96, kp = idx - row * 96;
    int vl = row >> 2, c = row & 3;
    int k0 = kp * 2;
    float f0 = 0.0f, f1 = 0.0f;
    if (c < 3) {
      if (k0 < 150) {
        f0 = Sh[vl][c * 150 + k0];
        f1 = Sh[vl][c * 150 + k0 + 1];
      } else if (k0 < 186) {
        f0 = Pd[k0 - 150][vl * 3 + c];
        f1 = Pd[k0 - 149][vl * 3 + c];
      }
    }
    uint u = (uint)f2bf(f0) | ((uint)f2bf(f1) << 16);
    int kb = kp >> 2, e = kp & 3;
    ((uint*)basis)[(size_t)(bx * 64 + row) * 96 + (((kb ^ (row & 7)) << 2) + e)] = u;
  }
  __syncthreads();  // protect Sh/Pd reuse across grid-stride iterations
}

static __device__ __forceinline__ void sj_unit(int bk, int t,
                                               const float* __restrict__ sdirs,
                                               const float* __restrict__ vtemp,
                                               const float* __restrict__ Jr,
                                               float* __restrict__ SJ) {
  __shared__ float JrL[5][CHUNK];
  int vstart = bk * CHUNK;
  int cnt = min(CHUNK, V_N - vstart);
  for (int idx = t; idx < 5 * CHUNK; idx += 256) {
    int j = idx / CHUNK, vi = idx % CHUNK;
    JrL[j][vi] = (vi < cnt) ? Jr[j * V_N + vstart + vi] : 0.0f;
  }
  __syncthreads();
  float acc0[5] = {0, 0, 0, 0, 0}, acc1[5] = {0, 0, 0, 0, 0};
  int c0 = t, c1 = t + 256;
#pragma unroll 4
  for (int vi = 0; vi < CHUNK; ++vi) {
    int v = min(vstart + vi, V_N - 1);
    float val0 = sdirs[(size_t)v * 450 + c0];
    float val1 = 0.0f;
    if (c1 < 450) val1 = sdirs[(size_t)v * 450 + c1];
    else if (c1 < 453) val1 = vtemp[(size_t)v * 3 + (c1 - 450)];
#pragma unroll
    for (int j = 0; j < 5; ++j) {
      float w = JrL[j][vi];
      acc0[j] = fmaf(w, val0, acc0[j]);
      acc1[j] = fmaf(w, val1, acc1[j]);
    }
  }
#pragma unroll
  for (int j = 0; j < 5; ++j) {
    atomicAdd(&SJ[j * 456 + c0], acc0[j]);
    if (c1 < 453) atomicAdd(&SJ[j * 456 + c1], acc1[j]);
  }
  __syncthreads();
}

static __device__ __forceinline__ void bext_unit(int chunk, int t,
                                                 const float* __restrict__ shp,
                                                 const float* __restrict__ expr,
                                                 ushort* __restrict__ bb) {
  int idx = chunk * 256 + t;
  int b = idx / 96, cp = idx - b * 96;
  int c0 = cp * 2;
  float f0 = 0.0f, f1 = 0.0f;
  if (c0 < 100) {
    f0 = shp[(size_t)b * 100 + c0];
    f1 = shp[(size_t)b * 100 + c0 + 1];
  } else if (c0 < 150) {
    f0 = expr[(size_t)b * 50 + (c0 - 100)];
    f1 = expr[(size_t)b * 50 + (c0 - 99)];
  }
  int r = b & 63;
  int kb = cp >> 2, e = cp & 3;
  ((uint*)bb)[(size_t)b * 96 + (((kb ^ (r & 7)) << 2) + e)] =
      (uint)f2bf(f0) | ((uint)f2bf(f1) << 16);
}

static __device__ __forceinline__ void jpose_unit(int u, int t,
                                                  const float* __restrict__ shp,
                                                  const float* __restrict__ expr,
                                                  const float* __restrict__ SJ,
                                                  const float* __restrict__ pose,
                                                  ushort* __restrict__ bb,
                                                  float* __restrict__ A,
                                                  float* __restrict__ out) {
  __shared__ float JtL[16][16];
  int g = t >> 4, r = t & 15;
  int b = u * 16 + g;
  if (r < 15) {
    int j = r / 3, k = r - j * 3;
    const float* SJr = SJ + j * 456;
    float acc = SJr[450 + k];
    const float* srow = shp + (size_t)b * 100;
    const float* erow = expr + (size_t)b * 50;
    for (int l = 0; l < 100; ++l) acc = fmaf(srow[l], SJr[k * 150 + l], acc);
    for (int l = 0; l < 50; ++l) acc = fmaf(erow[l], SJr[k * 150 + 100 + l], acc);
    JtL[g][r] = acc;
  }
  __syncthreads();
  if (r == 0) {
    float R[5][3][3];
#pragma unroll
    for (int j = 0; j < 5; ++j) {
      float rx = pose[(size_t)b * 15 + j * 3 + 0];
      float ry = pose[(size_t)b * 15 + j * 3 + 1];
      float rz = pose[(size_t)b * 15 + j * 3 + 2];
      float sx = rx + 1e-8f, sy = ry + 1e-8f, sz = rz + 1e-8f;
      float ang = sqrtf(sx * sx + sy * sy + sz * sz);
      float inv = 1.0f / ang;
      float ux = rx * inv, uy = ry * inv, uz = rz * inv;
      float c = cosf(ang), s = sinf(ang), omc = 1.0f - c;
      float K[3][3] = {{0.0f, -uz, uy}, {uz, 0.0f, -ux}, {-uy, ux, 0.0f}};
#pragma unroll
      for (int m = 0; m < 3; ++m)
#pragma unroll
        for (int n = 0; n < 3; ++n) {
          float k2 = 0.0f;
#pragma unroll
          for (int q = 0; q < 3; ++q) k2 += K[m][q] * K[q][n];
          R[j][m][n] = ((m == n) ? 1.0f : 0.0f) + s * K[m][n] + omc * k2;
        }
    }
    {
      float pf[36];
#pragma unroll
      for (int j = 1; j < 5; ++j)
#pragma unroll
        for (int m = 0; m < 3; ++m)
#pragma unroll
          for (int n = 0; n < 3; ++n)
            pf[(j - 1) * 9 + m * 3 + n] = R[j][m][n] - ((m == n) ? 1.0f : 0.0f);
      uint* bbu = (uint*)bb + (size_t)b * 96;
      int rr = b & 7;
#pragma unroll
      for (int q = 0; q < 18; ++q) {
        int cp = 75 + q;
        int kb = cp >> 2, e = cp & 3;
        bbu[((kb ^ rr) << 2) + e] = (uint)f2bf(pf[2 * q]) | ((uint)f2bf(pf[2 * q + 1]) << 16);
      }
    }
    float Jt[5][3];
#pragma unroll
    for (int j = 0; j < 5; ++j)
#pragma unroll
      for (int k = 0; k < 3; ++k) Jt[j][k] = JtL[g][j * 3 + k];
    const int par[5] = {0, 0, 1, 1, 1};
    float rel[5][3];
#pragma unroll
    for (int k = 0; k < 3; ++k) rel[0][k] = Jt[0][k];
#pragma unroll
    for (int j = 1; j < 5; ++j)
#pragma unroll
      for (int k = 0; k < 3; ++k) rel[j][k] = Jt[j][k] - Jt[par[j]][k];
    float Rg[5][3][3], tg[5][3];
#pragma unroll
    for (int m = 0; m < 3; ++m) {
#pragma unroll
      for (int n = 0; n < 3; ++n) Rg[0][m][n] = R[0][m][n];
      tg[0][m] = rel[0][m];
    }
#pragma unroll
    for (int j = 1; j < 5; ++j) {
      int p = par[j];
#pragma unroll
      for (int m = 0; m < 3; ++m) {
        float t2 = tg[p][m];
#pragma unroll
        for (int n = 0; n < 3; ++n) {
          float s = 0.0f;
#pragma unroll
          for (int q = 0; q < 3; ++q) s = fmaf(Rg[p][m][q], R[j][q][n], s);
          Rg[j][m][n] = s;
          t2 = fmaf(Rg[p][m][n], rel[j][n], t2);
        }
        tg[j][m] = t2;
      }
    }
#pragma unroll
    for (int j = 0; j < 5; ++j)
#pragma unroll
      for (int k = 0; k < 3; ++k)
        out[(size_t)B_N * V_N * 3 + ((size_t)b * 5 + j) * 3 + k] = tg[j][k];
    float Af[5][12];
#pragma unroll
    for (int j = 0; j < 5; ++j)
#pragma unroll
      for (int m = 0; m < 3; ++m) {
        float tj = 0.0f;
#pragma unroll
        for (int n = 0; n < 3; ++n) {
          Af[j][m * 4 + n] = Rg[j][m][n];
          tj = fmaf(Rg[j][m][n], Jt[j][n], tj);
        }
        Af[j][m * 4 + 3] = tg[j][m] - tj;
      }
    float* Ab = A + (size_t)b * 64;
#pragma unroll
    for (int q = 0; q < 12; ++q) Ab[q] = Af[0][q];
#pragma unroll
    for (int j = 1; j < 5; ++j)
#pragma unroll
      for (int q = 0; q < 12; ++q) Ab[j * 12 + q] = Af[j][q] - Af[0][q];
  }
  __syncthreads();
}

// ---------------- cooperative fused prologue ----------------
__global__ __launch_bounds__(256) void k_prologue(const float* __restrict__ sdirs,
                                                  const float* __restrict__ pdirs,
                                                  const float* __restrict__ vtemp,
                                                  const float* __restrict__ Jr,
                                                  const float* __restrict__ shp,
                                                  const float* __restrict__ expr,
                                                  const float* __restrict__ pose,
                                                  ushort* __restrict__ basis,
                                                  float* __restrict__ SJ,
                                                  ushort* __restrict__ bb,
                                                  float* __restrict__ A,
                                                  float* __restrict__ out) {
  cg::grid_group grid = cg::this_grid();
  int t = threadIdx.x;
  for (int id = blockIdx.x * 256 + t; id < 2280; id += gridDim.x * 256) SJ[id] = 0.0f;
  grid.sync();
  for (int u = blockIdx.x; u < 314 + NSJB + 768; u += gridDim.x) {
    if (u < 314) basis_unit(u, t, sdirs, pdirs, basis);
    else if (u < 314 + NSJB) sj_unit(u - 314, t, sdirs, vtemp, Jr, SJ);
    else bext_unit(u - 314 - NSJB, t, shp, expr, bb);
  }
  grid.sync();
  for (int u = blockIdx.x; u < 128; u += gridDim.x)
    jpose_unit(u, t, shp, expr, SJ, pose, bb, A, out);
}

// ---------------- fallback (non-cooperative) kernels ----------------
__global__ void k_zero(float* __restrict__ SJ) {
  int id = blockIdx.x * 256 + threadIdx.x;
  if (id < 2280) SJ[id] = 0.0f;
}

__global__ __launch_bounds__(256) void k_pre(const float* __restrict__ sdirs,
                                             const float* __restrict__ pdirs,
                                             const float* __restrict__ vtemp,
                                             const float* __restrict__ Jr,
                                             const float* __restrict__ shp,
                                             const float* __restrict__ expr,
                                             ushort* __restrict__ basis,
                                             float* __restrict__ SJ,
                                             ushort* __restrict__ bb) {
  int blk = blockIdx.x, t = threadIdx.x;
  if (blk < 314) basis_unit(blk, t, sdirs, pdirs, basis);
  else if (blk < 314 + NSJB) sj_unit(blk - 314, t, sdirs, vtemp, Jr, SJ);
  else bext_unit(blk - 314 - NSJB, t, shp, expr, bb);
}

__global__ __launch_bounds__(256) void k_jpose(const float* __restrict__ shp,
                                               const float* __restrict__ expr,
                                               const float* __restrict__ SJ,
                                               const float* __restrict__ pose,
                                               ushort* __restrict__ bb,
                                               float* __restrict__ A,
                                               float* __restrict__ out) {
  jpose_unit(blockIdx.x, threadIdx.x, shp, expr, SJ, pose, bb, A, out);
}

// ================= k_main: MFMA GEMM + fused skinning (R14-proven) =================
__global__ __launch_bounds__(512, 6) void k_main(const ushort* __restrict__ basis,
                                                 const ushort* __restrict__ bb,
                                                 const float* __restrict__ Amat,
                                                 const float* __restrict__ lw,
                                                 const float* __restrict__ vtemp,
                                                 float* __restrict__ out) {
  __shared__ alignas(16) ushort AL[64 * 192];
  __shared__ alignas(16) ushort BL[64 * 192];
  float* AmL = (float*)AL;
  int t = threadIdx.x;
  int bx = blockIdx.y;
  int by = blockIdx.x;
  int b0 = by * 64;
  int lane = t & 63;
  int w = __builtin_amdgcn_readfirstlane(t >> 6);
  {
    const char* gA = (const char*)(basis + (size_t)bx * 64 * 192);
    const char* gB = (const char*)(bb + (size_t)b0 * 192);
#pragma unroll
    for (int i = 0; i < 3; ++i) {
      int chunk = w * 3 + i;
      int off = chunk * 1024 + lane * 16;
      __builtin_amdgcn_global_load_lds(
          (const __attribute__((address_space(1))) uint*)(gA + off),
          (__attribute__((address_space(3))) uint*)((char*)&AL[0] + chunk * 1024), 16, 0, 0);
      __builtin_amdgcn_global_load_lds(
          (const __attribute__((address_space(1))) uint*)(gB + off),
          (__attribute__((address_space(3))) uint*)((char*)&BL[0] + chunk * 1024), 16, 0, 0);
    }
  }
  __syncthreads();
  int wm = w >> 1, wn = w & 1;
  int lm = lane & 15, g = lane >> 4;
  f32x4 acc0 = {0.f, 0.f, 0.f, 0.f}, acc1 = {0.f, 0.f, 0.f, 0.f};
  const int ar = wm * 16 + lm;
  const int br0 = wn * 32 + lm;
  const int br1 = wn * 32 + 16 + lm;
#pragma unroll
  for (int ks = 0; ks < 6; ++ks) {
    int kb = ks * 4 + g;
    short8 af = *(const short8*)(&AL[(ar * 24 + (kb ^ (ar & 7))) * 8]);
    short8 bf0 = *(const short8*)(&BL[(br0 * 24 + (kb ^ (br0 & 7))) * 8]);
    short8 bf1 = *(const short8*)(&BL[(br1 * 24 + (kb ^ (br1 & 7))) * 8]);
    acc0 = __builtin_amdgcn_mfma_f32_16x16x32_bf16(af, bf0, acc0, 0, 0, 0);
    acc1 = __builtin_amdgcn_mfma_f32_16x16x32_bf16(af, bf1, acc1, 0, 0, 0);
  }
  int v = bx * 16 + wm * 4 + g;
  bool valid = v < V_N;
  int vv = valid ? v : 0;
  float wv[4];
#pragma unroll
  for (int j = 0; j < 4; ++j) wv[j] = lw[(size_t)vv * 5 + 1 + j];
  float vt0 = vtemp[(size_t)vv * 3 + 0];
  float vt1 = vtemp[(size_t)vv * 3 + 1];
  float vt2 = vtemp[(size_t)vv * 3 + 2];
  __syncthreads();
#pragma unroll
  for (int i = 0; i < 2; ++i) {
    int c = t + i * 512;
    int r = c / 16, q = (c % 16) * 4;
    *(f32x4*)(&AmL[r * 68 + q]) = *(const f32x4*)(&Amat[((size_t)(b0 + r)) * 64 + q]);
  }
  __syncthreads();
#pragma unroll
  for (int ni = 0; ni < 2; ++ni) {
    f32x4 p = ni ? acc1 : acc0;
    int bl = wn * 32 + ni * 16 + lm;
    const float* Ar = &AmL[bl * 68];
    f32x4 T0 = *(const f32x4*)(Ar + 0);
    f32x4 T1 = *(const f32x4*)(Ar + 4);
    f32x4 T2 = *(const f32x4*)(Ar + 8);
#pragma unroll
    for (int j = 1; j < 5; ++j) {
      f32x4 d0 = *(const f32x4*)(Ar + j * 12 + 0);
      f32x4 d1 = *(const f32x4*)(Ar + j * 12 + 4);
      f32x4 d2 = *(const f32x4*)(Ar + j * 12 + 8);
      float wjv = wv[j - 1];
#pragma unroll
      for (int c = 0; c < 4; ++c) {
        T0[c] = fmaf(wjv, d0[c], T0[c]);
        T1[c] = fmaf(wjv, d1[c], T1[c]);
        T2[c] = fmaf(wjv, d2[c], T2[c]);
      }
    }
    float x = p[0] + vt0, y = p[1] + vt1, z = p[2] + vt2;
    float ox = fmaf(T0[0], x, fmaf(T0[1], y, fmaf(T0[2], z, T0[3])));
    float oy = fmaf(T1[0], x, fmaf(T1[1], y, fmaf(T1[2], z, T1[3])));
    float oz = fmaf(T2[0], x, fmaf(T2[1], y, fmaf(T2[2], z, T2[3])));
    if (valid) {
      size_t o = ((size_t)(b0 + bl)) * V3_N + (size_t)v * 3;
      out[o + 0] = ox;
      out[o + 1] = oy;
      out[o + 2] = oz;
    }
  }
}

extern "C" void kernel_launch(void* const* d_in, const int* in_sizes, int n_in,
                              void* d_out, int out_size, void* d_ws, size_t ws_size,
                              hipStream_t stream) {
  const float* shp = (const float*)d_in[0];
  const float* expr = (const float*)d_in[1];
  const float* pose = (const float*)d_in[2];
  const float* vtemp = (const float*)d_in[3];
  const float* sdirs = (const float*)d_in[4];
  const float* pdirs = (const float*)d_in[5];
  const float* Jr = (const float*)d_in[6];
  const float* lw = (const float*)d_in[7];
  float* out = (float*)d_out;
  float* wsf = (float*)d_ws;

  const size_t OFF_SJ = 358400;
  const size_t OFF_A = 786688;
  const size_t OFF_BB = 917760;
  const size_t OFF_BASIS = 1114368;
  float* SJ = wsf + OFF_SJ;
  float* A = wsf + OFF_A;
  ushort* bb = (ushort*)(wsf + OFF_BB);
  ushort* basis = (ushort*)(wsf + OFF_BASIS);

  // deterministic occupancy-bounded cooperative grid
  int maxB = 0;
  hipError_t qe = hipOccupancyMaxActiveBlocksPerMultiprocessor(&maxB, k_prologue, 256, 0);
  int coopGrid = 512;
  if (qe == hipSuccess && maxB > 0) {
    long cap = (long)maxB * 256;  // 256 CUs
    coopGrid = (int)(cap < 1239 ? cap : 1239);
  }

  const float* sdirs_c = sdirs;
  const float* pdirs_c = pdirs;
  const float* vtemp_c = vtemp;
  const float* Jr_c = Jr;
  const float* shp_c = shp;
  const float* expr_c = expr;
  const float* pose_c = pose;
  void* kargs[] = {(void*)&sdirs_c, (void*)&pdirs_c, (void*)&vtemp_c, (void*)&Jr_c,
                   (void*)&shp_c,   (void*)&expr_c,  (void*)&pose_c,  (void*)&basis,
                   (void*)&SJ,      (void*)&bb,      (void*)&A,       (void*)&out};
  hipError_t ce = hipLaunchCooperativeKernel((void*)k_prologue, dim3(coopGrid), dim3(256),
                                             kargs, 0, stream);
  if (ce != hipSuccess) {
    // fallback: three regular launches (identical semantics)
    hipLaunchKernelGGL(k_zero, dim3(9), dim3(256), 0, stream, SJ);
    hipLaunchKernelGGL(k_pre, dim3(314 + NSJB + 768), dim3(256), 0, stream,
                       sdirs, pdirs, vtemp, Jr, shp, expr, basis, SJ, bb);
    hipLaunchKernelGGL(k_jpose, dim3(128), dim3(256), 0, stream,
                       shp, expr, SJ, pose, bb, A, out);
  }
  hipLaunchKernelGGL(k_main, dim3(32, 314), dim3(512), 0, stream,
                     basis, bb, A, lw, vtemp, out);
}

// Round 16
// 120.652 us; speedup vs baseline: 1.4191x; 1.4191x over previous
//
#include <hip/hip_runtime.h>
#include <hip/hip_bf16.h>
#include <math.h>

#define B_N 2048
#define V_N 5023
#define V3_N 15069
#define CHUNK 32

typedef float f32x4 __attribute__((ext_vector_type(4)));
typedef short short8 __attribute__((ext_vector_type(8)));

static __device__ __forceinline__ ushort f2bf(float f) {
  __hip_bfloat16 h = __float2bfloat16(f);
  return *reinterpret_cast<ushort*>(&h);
}

// ================= L0: zero SJ =================
__global__ void k_zero(float* __restrict__ SJ) {
  int id = blockIdx.x * 256 + threadIdx.x;
  if (id < 2280) SJ[id] = 0.0f;
}

// ================= L1: fused prologue =================
// blocks [0,314): basis transpose + SJ partial (shares the staged Sh tile);
// blocks [314,1082): bext bf16 (pre-swizzled).
__global__ __launch_bounds__(256) void k_pre(const float* __restrict__ sdirs,
                                             const float* __restrict__ pdirs,
                                             const float* __restrict__ vtemp,
                                             const float* __restrict__ Jr,
                                             const float* __restrict__ shp,
                                             const float* __restrict__ expr,
                                             ushort* __restrict__ basis,
                                             float* __restrict__ SJ,
                                             ushort* __restrict__ bb) {
  __shared__ float Sh[16][452];
  __shared__ float Pd[36][48];
  __shared__ float JrS[5][16];
  int t = threadIdx.x, blk = blockIdx.x;
  if (blk < 314) {
    int bx = blk, v0 = bx * 16;
    for (int idx = t; idx < 16 * 450; idx += 256) {
      int r = idx / 450, c = idx - r * 450;
      int v = v0 + r;
      Sh[r][c] = (v < V_N) ? sdirs[(size_t)v * 450 + c] : 0.0f;
    }
    for (int idx = t; idx < 36 * 48; idx += 256) {
      int p = idx / 48, c = idx - p * 48;
      int v3 = v0 * 3 + c;
      Pd[p][c] = (v3 < V3_N) ? pdirs[(size_t)p * V3_N + v3] : 0.0f;
    }
    if (t < 80) {
      int j = t / 16, r = t - j * 16;
      int v = v0 + r;
      JrS[j][r] = (v < V_N) ? Jr[j * V_N + v] : 0.0f;
    }
    __syncthreads();
    // ---- basis output (pre-swizzled bf16) ----
    for (int idx = t; idx < 64 * 96; idx += 256) {
      int row = idx / 96, kp = idx - row * 96;
      int vl = row >> 2, c = row & 3;
      int k0 = kp * 2;
      float f0 = 0.0f, f1 = 0.0f;
      if (c < 3) {
        if (k0 < 150) {
          f0 = Sh[vl][c * 150 + k0];
          f1 = Sh[vl][c * 150 + k0 + 1];
        } else if (k0 < 186) {
          f0 = Pd[k0 - 150][vl * 3 + c];
          f1 = Pd[k0 - 149][vl * 3 + c];
        }
      }
      uint u = (uint)f2bf(f0) | ((uint)f2bf(f1) << 16);
      int kb = kp >> 2, e = kp & 3;
      ((uint*)basis)[(size_t)(bx * 64 + row) * 96 + (((kb ^ (row & 7)) << 2) + e)] = u;
    }
    // ---- SJ partial for this block's 16 vertices (reuses Sh) ----
#pragma unroll
    for (int pass = 0; pass < 2; ++pass) {
      int c = t + pass * 256;
      if (c < 453) {
        float acc[5] = {0, 0, 0, 0, 0};
#pragma unroll 4
        for (int r = 0; r < 16; ++r) {
          float val;
          if (c < 450) {
            val = Sh[r][c];
          } else {
            int v = v0 + r;
            val = (v < V_N) ? vtemp[(size_t)v * 3 + (c - 450)] : 0.0f;
          }
#pragma unroll
          for (int j = 0; j < 5; ++j) acc[j] = fmaf(JrS[j][r], val, acc[j]);
        }
#pragma unroll
        for (int j = 0; j < 5; ++j) atomicAdd(&SJ[j * 456 + c], acc[j]);
      }
    }
  } else {
    // ---- bext bf16 (cols 0..149; zero 150..191), pre-swizzled ----
    int idx = (blk - 314) * 256 + t;
    int b = idx / 96, cp = idx - b * 96;
    int c0 = cp * 2;
    float f0 = 0.0f, f1 = 0.0f;
    if (c0 < 100) {
      f0 = shp[(size_t)b * 100 + c0];
      f1 = shp[(size_t)b * 100 + c0 + 1];
    } else if (c0 < 150) {
      f0 = expr[(size_t)b * 50 + (c0 - 100)];
      f1 = expr[(size_t)b * 50 + (c0 - 99)];
    }
    int r = b & 63;
    int kb = cp >> 2, e = cp & 3;
    ((uint*)bb)[(size_t)b * 96 + (((kb ^ (r & 7)) << 2) + e)] =
        (uint)f2bf(f0) | ((uint)f2bf(f1) << 16);
  }
}

// ================= L2: fused Jts + pose (writes bb pose-features pre-swizzled) =================
__global__ __launch_bounds__(256) void k_jpose(const float* __restrict__ shp,
                                               const float* __restrict__ expr,
                                               const float* __restrict__ SJ,
                                               const float* __restrict__ pose,
                                               ushort* __restrict__ bb,
                                               float* __restrict__ A,
                                               float* __restrict__ out) {
  __shared__ float JtL[16][16];
  int t = threadIdx.x;
  int g = t >> 4, r = t & 15;
  int b = blockIdx.x * 16 + g;
  if (r < 15) {
    int j = r / 3, k = r - j * 3;
    const float* SJr = SJ + j * 456;
    float acc = SJr[450 + k];
    const float* srow = shp + (size_t)b * 100;
    const float* erow = expr + (size_t)b * 50;
    for (int l = 0; l < 100; ++l) acc = fmaf(srow[l], SJr[k * 150 + l], acc);
    for (int l = 0; l < 50; ++l) acc = fmaf(erow[l], SJr[k * 150 + 100 + l], acc);
    JtL[g][r] = acc;
  }
  __syncthreads();
  if (r != 0) return;
  float R[5][3][3];
#pragma unroll
  for (int j = 0; j < 5; ++j) {
    float rx = pose[(size_t)b * 15 + j * 3 + 0];
    float ry = pose[(size_t)b * 15 + j * 3 + 1];
    float rz = pose[(size_t)b * 15 + j * 3 + 2];
    float sx = rx + 1e-8f, sy = ry + 1e-8f, sz = rz + 1e-8f;
    float ang = sqrtf(sx * sx + sy * sy + sz * sz);
    float inv = 1.0f / ang;
    float ux = rx * inv, uy = ry * inv, uz = rz * inv;
    float c = cosf(ang), s = sinf(ang), omc = 1.0f - c;
    float K[3][3] = {{0.0f, -uz, uy}, {uz, 0.0f, -ux}, {-uy, ux, 0.0f}};
#pragma unroll
    for (int m = 0; m < 3; ++m)
#pragma unroll
      for (int n = 0; n < 3; ++n) {
        float k2 = 0.0f;
#pragma unroll
        for (int q = 0; q < 3; ++q) k2 += K[m][q] * K[q][n];
        R[j][m][n] = ((m == n) ? 1.0f : 0.0f) + s * K[m][n] + omc * k2;
      }
  }
  {
    float pf[36];
#pragma unroll
    for (int j = 1; j < 5; ++j)
#pragma unroll
      for (int m = 0; m < 3; ++m)
#pragma unroll
        for (int n = 0; n < 3; ++n)
          pf[(j - 1) * 9 + m * 3 + n] = R[j][m][n] - ((m == n) ? 1.0f : 0.0f);
    uint* bbu = (uint*)bb + (size_t)b * 96;
    int rr = b & 7;
#pragma unroll
    for (int q = 0; q < 18; ++q) {
      int cp = 75 + q;
      int kb = cp >> 2, e = cp & 3;
      bbu[((kb ^ rr) << 2) + e] = (uint)f2bf(pf[2 * q]) | ((uint)f2bf(pf[2 * q + 1]) << 16);
    }
  }
  float Jt[5][3];
#pragma unroll
  for (int j = 0; j < 5; ++j)
#pragma unroll
    for (int k = 0; k < 3; ++k) Jt[j][k] = JtL[g][j * 3 + k];
  const int par[5] = {0, 0, 1, 1, 1};
  float rel[5][3];
#pragma unroll
  for (int k = 0; k < 3; ++k) rel[0][k] = Jt[0][k];
#pragma unroll
  for (int j = 1; j < 5; ++j)
#pragma unroll
    for (int k = 0; k < 3; ++k) rel[j][k] = Jt[j][k] - Jt[par[j]][k];
  float Rg[5][3][3], tg[5][3];
#pragma unroll
  for (int m = 0; m < 3; ++m) {
#pragma unroll
    for (int n = 0; n < 3; ++n) Rg[0][m][n] = R[0][m][n];
    tg[0][m] = rel[0][m];
  }
#pragma unroll
  for (int j = 1; j < 5; ++j) {
    int p = par[j];
#pragma unroll
    for (int m = 0; m < 3; ++m) {
      float t2 = tg[p][m];
#pragma unroll
      for (int n = 0; n < 3; ++n) {
        float s = 0.0f;
#pragma unroll
        for (int q = 0; q < 3; ++q) s = fmaf(Rg[p][m][q], R[j][q][n], s);
        Rg[j][m][n] = s;
        t2 = fmaf(Rg[p][m][n], rel[j][n], t2);
      }
      tg[j][m] = t2;
    }
  }
#pragma unroll
  for (int j = 0; j < 5; ++j)
#pragma unroll
    for (int k = 0; k < 3; ++k)
      out[(size_t)B_N * V_N * 3 + ((size_t)b * 5 + j) * 3 + k] = tg[j][k];
  float Af[5][12];
#pragma unroll
  for (int j = 0; j < 5; ++j)
#pragma unroll
    for (int m = 0; m < 3; ++m) {
      float tj = 0.0f;
#pragma unroll
      for (int n = 0; n < 3; ++n) {
        Af[j][m * 4 + n] = Rg[j][m][n];
        tj = fmaf(Rg[j][m][n], Jt[j][n], tj);
      }
      Af[j][m * 4 + 3] = tg[j][m] - tj;
    }
  float* Ab = A + (size_t)b * 64;
#pragma unroll
  for (int q = 0; q < 12; ++q) Ab[q] = Af[0][q];
#pragma unroll
  for (int j = 1; j < 5; ++j)
#pragma unroll
    for (int q = 0; q < 12; ++q) Ab[j * 12 + q] = Af[j][q] - Af[0][q];
}

// ================= L3: MFMA GEMM + fused skinning (R14-proven) =================
// grid (32 batch-tiles FAST, 314 vertex-tiles). Pre-swizzled global data; linear async
// staging via global_load_lds width=16 (24 x 1KB chunks/tile; wave w -> chunks 3w..3w+2).
__global__ __launch_bounds__(512, 6) void k_main(const ushort* __restrict__ basis,
                                                 const ushort* __restrict__ bb,
                                                 const float* __restrict__ Amat,
                                                 const float* __restrict__ lw,
                                                 const float* __restrict__ vtemp,
                                                 float* __restrict__ out) {
  __shared__ alignas(16) ushort AL[64 * 192];
  __shared__ alignas(16) ushort BL[64 * 192];
  float* AmL = (float*)AL;
  int t = threadIdx.x;
  int bx = blockIdx.y;
  int by = blockIdx.x;
  int b0 = by * 64;
  int lane = t & 63;
  int w = __builtin_amdgcn_readfirstlane(t >> 6);
  {
    const char* gA = (const char*)(basis + (size_t)bx * 64 * 192);
    const char* gB = (const char*)(bb + (size_t)b0 * 192);
#pragma unroll
    for (int i = 0; i < 3; ++i) {
      int chunk = w * 3 + i;
      int off = chunk * 1024 + lane * 16;
      __builtin_amdgcn_global_load_lds(
          (const __attribute__((address_space(1))) uint*)(gA + off),
          (__attribute__((address_space(3))) uint*)((char*)&AL[0] + chunk * 1024), 16, 0, 0);
      __builtin_amdgcn_global_load_lds(
          (const __attribute__((address_space(1))) uint*)(gB + off),
          (__attribute__((address_space(3))) uint*)((char*)&BL[0] + chunk * 1024), 16, 0, 0);
    }
  }
  __syncthreads();
  int wm = w >> 1, wn = w & 1;
  int lm = lane & 15, g = lane >> 4;
  f32x4 acc0 = {0.f, 0.f, 0.f, 0.f}, acc1 = {0.f, 0.f, 0.f, 0.f};
  const int ar = wm * 16 + lm;
  const int br0 = wn * 32 + lm;
  const int br1 = wn * 32 + 16 + lm;
#pragma unroll
  for (int ks = 0; ks < 6; ++ks) {
    int kb = ks * 4 + g;
    short8 af = *(const short8*)(&AL[(ar * 24 + (kb ^ (ar & 7))) * 8]);
    short8 bf0 = *(const short8*)(&BL[(br0 * 24 + (kb ^ (br0 & 7))) * 8]);
    short8 bf1 = *(const short8*)(&BL[(br1 * 24 + (kb ^ (br1 & 7))) * 8]);
    acc0 = __builtin_amdgcn_mfma_f32_16x16x32_bf16(af, bf0, acc0, 0, 0, 0);
    acc1 = __builtin_amdgcn_mfma_f32_16x16x32_bf16(af, bf1, acc1, 0, 0, 0);
  }
  int v = bx * 16 + wm * 4 + g;
  bool valid = v < V_N;
  int vv = valid ? v : 0;
  float wv[4];
#pragma unroll
  for (int j = 0; j < 4; ++j) wv[j] = lw[(size_t)vv * 5 + 1 + j];
  float vt0 = vtemp[(size_t)vv * 3 + 0];
  float vt1 = vtemp[(size_t)vv * 3 + 1];
  float vt2 = vtemp[(size_t)vv * 3 + 2];
  __syncthreads();
#pragma unroll
  for (int i = 0; i < 2; ++i) {
    int c = t + i * 512;
    int r = c / 16, q = (c % 16) * 4;
    *(f32x4*)(&AmL[r * 68 + q]) = *(const f32x4*)(&Amat[((size_t)(b0 + r)) * 64 + q]);
  }
  __syncthreads();
#pragma unroll
  for (int ni = 0; ni < 2; ++ni) {
    f32x4 p = ni ? acc1 : acc0;
    int bl = wn * 32 + ni * 16 + lm;
    const float* Ar = &AmL[bl * 68];
    f32x4 T0 = *(const f32x4*)(Ar + 0);
    f32x4 T1 = *(const f32x4*)(Ar + 4);
    f32x4 T2 = *(const f32x4*)(Ar + 8);
#pragma unroll
    for (int j = 1; j < 5; ++j) {
      f32x4 d0 = *(const f32x4*)(Ar + j * 12 + 0);
      f32x4 d1 = *(const f32x4*)(Ar + j * 12 + 4);
      f32x4 d2 = *(const f32x4*)(Ar + j * 12 + 8);
      float wjv = wv[j - 1];
#pragma unroll
      for (int c = 0; c < 4; ++c) {
        T0[c] = fmaf(wjv, d0[c], T0[c]);
        T1[c] = fmaf(wjv, d1[c], T1[c]);
        T2[c] = fmaf(wjv, d2[c], T2[c]);
      }
    }
    float x = p[0] + vt0, y = p[1] + vt1, z = p[2] + vt2;
    float ox = fmaf(T0[0], x, fmaf(T0[1], y, fmaf(T0[2], z, T0[3])));
    float oy = fmaf(T1[0], x, fmaf(T1[1], y, fmaf(T1[2], z, T1[3])));
    float oz = fmaf(T2[0], x, fmaf(T2[1], y, fmaf(T2[2], z, T2[3])));
    if (valid) {
      size_t o = ((size_t)(b0 + bl)) * V3_N + (size_t)v * 3;
      out[o + 0] = ox;
      out[o + 1] = oy;
      out[o + 2] = oz;
    }
  }
}

extern "C" void kernel_launch(void* const* d_in, const int* in_sizes, int n_in,
                              void* d_out, int out_size, void* d_ws, size_t ws_size,
                              hipStream_t stream) {
  const float* shp = (const float*)d_in[0];
  const float* expr = (const float*)d_in[1];
  const float* pose = (const float*)d_in[2];
  const float* vtemp = (const float*)d_in[3];
  const float* sdirs = (const float*)d_in[4];
  const float* pdirs = (const float*)d_in[5];
  const float* Jr = (const float*)d_in[6];
  const float* lw = (const float*)d_in[7];
  float* out = (float*)d_out;
  float* wsf = (float*)d_ws;

  const size_t OFF_SJ = 358400;
  const size_t OFF_A = 786688;
  const size_t OFF_BB = 917760;
  const size_t OFF_BASIS = 1114368;
  float* SJ = wsf + OFF_SJ;
  float* A = wsf + OFF_A;
  ushort* bb = (ushort*)(wsf + OFF_BB);
  ushort* basis = (ushort*)(wsf + OFF_BASIS);

  hipLaunchKernelGGL(k_zero, dim3(9), dim3(256), 0, stream, SJ);
  hipLaunchKernelGGL(k_pre, dim3(314 + 768), dim3(256), 0, stream,
                     sdirs, pdirs, vtemp, Jr, shp, expr, basis, SJ, bb);
  hipLaunchKernelGGL(k_jpose, dim3(128), dim3(256), 0, stream,
                     shp, expr, SJ, pose, bb, A, out);
  hipLaunchKernelGGL(k_main, dim3(32, 314), dim3(512), 0, stream,
                     basis, bb, A, lw, vtemp, out);
}

// Round 17
// 107.970 us; speedup vs baseline: 1.5858x; 1.1175x over previous
//
#include <hip/hip_runtime.h>
#include <hip/hip_bf16.h>
#include <math.h>

#define B_N 2048
#define V_N 5023
#define V3_N 15069
#define NSJB 157
#define CHUNK 32

typedef float f32x4 __attribute__((ext_vector_type(4)));
typedef short short8 __attribute__((ext_vector_type(8)));

static __device__ __forceinline__ ushort f2bf(float f) {
  __hip_bfloat16 h = __float2bfloat16(f);
  return *reinterpret_cast<ushort*>(&h);
}

// ================= L0: zero SJ =================
__global__ void k_zero(float* __restrict__ SJ) {
  int id = blockIdx.x * 256 + threadIdx.x;
  if (id < 2280) SJ[id] = 0.0f;
}

// ================= L1: fused independent prologue =================
// blocks [0,314): basis (pre-swizzled); [314,471): SJ partials (atomic); [471,1239): bext bf16 (pre-swizzled)
// Swizzle: within each 64-row tile, 16B-chunk kb of row r stored at chunk (kb ^ (r&7)).
__global__ __launch_bounds__(256) void k_pre(const float* __restrict__ sdirs,
                                             const float* __restrict__ pdirs,
                                             const float* __restrict__ vtemp,
                                             const float* __restrict__ Jr,
                                             const float* __restrict__ shp,
                                             const float* __restrict__ expr,
                                             ushort* __restrict__ basis,
                                             float* __restrict__ SJ,
                                             ushort* __restrict__ bb) {
  __shared__ float Sh[16][452];
  __shared__ float Pd[36][48];
  int t = threadIdx.x, blk = blockIdx.x;
  if (blk < 314) {
    int bx = blk, v0 = bx * 16;
    for (int idx = t; idx < 16 * 450; idx += 256) {
      int r = idx / 450, c = idx - r * 450;
      int v = v0 + r;
      Sh[r][c] = (v < V_N) ? sdirs[(size_t)v * 450 + c] : 0.0f;
    }
    for (int idx = t; idx < 36 * 48; idx += 256) {
      int p = idx / 48, c = idx - p * 48;
      int v3 = v0 * 3 + c;
      Pd[p][c] = (v3 < V3_N) ? pdirs[(size_t)p * V3_N + v3] : 0.0f;
    }
    __syncthreads();
    for (int idx = t; idx < 64 * 96; idx += 256) {
      int row = idx / 96, kp = idx - row * 96;
      int vl = row >> 2, c = row & 3;
      int k0 = kp * 2;
      float f0 = 0.0f, f1 = 0.0f;
      if (c < 3) {
        if (k0 < 150) {
          f0 = Sh[vl][c * 150 + k0];
          f1 = Sh[vl][c * 150 + k0 + 1];
        } else if (k0 < 186) {
          f0 = Pd[k0 - 150][vl * 3 + c];
          f1 = Pd[k0 - 149][vl * 3 + c];
        }
      }
      uint u = (uint)f2bf(f0) | ((uint)f2bf(f1) << 16);
      int kb = kp >> 2, e = kp & 3;
      ((uint*)basis)[(size_t)(bx * 64 + row) * 96 + (((kb ^ (row & 7)) << 2) + e)] = u;
    }
  } else if (blk < 314 + NSJB) {
    float (*JrL)[CHUNK] = (float(*)[CHUNK]) & Sh[0][0];
    int bk = blk - 314;
    int vstart = bk * CHUNK;
    int cnt = min(CHUNK, V_N - vstart);
    for (int idx = t; idx < 5 * CHUNK; idx += 256) {
      int j = idx / CHUNK, vi = idx % CHUNK;
      JrL[j][vi] = (vi < cnt) ? Jr[j * V_N + vstart + vi] : 0.0f;
    }
    __syncthreads();
    float acc0[5] = {0, 0, 0, 0, 0}, acc1[5] = {0, 0, 0, 0, 0};
    int c0 = t, c1 = t + 256;
#pragma unroll 4
    for (int vi = 0; vi < CHUNK; ++vi) {
      int v = min(vstart + vi, V_N - 1);
      float val0 = sdirs[(size_t)v * 450 + c0];
      float val1 = 0.0f;
      if (c1 < 450) val1 = sdirs[(size_t)v * 450 + c1];
      else if (c1 < 453) val1 = vtemp[(size_t)v * 3 + (c1 - 450)];
#pragma unroll
      for (int j = 0; j < 5; ++j) {
        float w = JrL[j][vi];
        acc0[j] = fmaf(w, val0, acc0[j]);
        acc1[j] = fmaf(w, val1, acc1[j]);
      }
    }
#pragma unroll
    for (int j = 0; j < 5; ++j) {
      atomicAdd(&SJ[j * 456 + c0], acc0[j]);
      if (c1 < 453) atomicAdd(&SJ[j * 456 + c1], acc1[j]);
    }
  } else {
    int idx = (blk - 314 - NSJB) * 256 + t;
    int b = idx / 96, cp = idx - b * 96;
    int c0 = cp * 2;
    float f0 = 0.0f, f1 = 0.0f;
    if (c0 < 100) {
      f0 = shp[(size_t)b * 100 + c0];
      f1 = shp[(size_t)b * 100 + c0 + 1];
    } else if (c0 < 150) {
      f0 = expr[(size_t)b * 50 + (c0 - 100)];
      f1 = expr[(size_t)b * 50 + (c0 - 99)];
    }
    int r = b & 63;
    int kb = cp >> 2, e = cp & 3;
    ((uint*)bb)[(size_t)b * 96 + (((kb ^ (r & 7)) << 2) + e)] =
        (uint)f2bf(f0) | ((uint)f2bf(f1) << 16);
  }
}

// ================= L2: fused Jts + pose (writes bb pose-features pre-swizzled) =================
__global__ __launch_bounds__(256) void k_jpose(const float* __restrict__ shp,
                                               const float* __restrict__ expr,
                                               const float* __restrict__ SJ,
                                               const float* __restrict__ pose,
                                               ushort* __restrict__ bb,
                                               float* __restrict__ A,
                                               float* __restrict__ out) {
  __shared__ float JtL[16][16];
  int t = threadIdx.x;
  int g = t >> 4, r = t & 15;
  int b = blockIdx.x * 16 + g;
  if (r < 15) {
    int j = r / 3, k = r - j * 3;
    const float* SJr = SJ + j * 456;
    float acc = SJr[450 + k];
    const float* srow = shp + (size_t)b * 100;
    const float* erow = expr + (size_t)b * 50;
    for (int l = 0; l < 100; ++l) acc = fmaf(srow[l], SJr[k * 150 + l], acc);
    for (int l = 0; l < 50; ++l) acc = fmaf(erow[l], SJr[k * 150 + 100 + l], acc);
    JtL[g][r] = acc;
  }
  __syncthreads();
  if (r != 0) return;
  float R[5][3][3];
#pragma unroll
  for (int j = 0; j < 5; ++j) {
    float rx = pose[(size_t)b * 15 + j * 3 + 0];
    float ry = pose[(size_t)b * 15 + j * 3 + 1];
    float rz = pose[(size_t)b * 15 + j * 3 + 2];
    float sx = rx + 1e-8f, sy = ry + 1e-8f, sz = rz + 1e-8f;
    float ang = sqrtf(sx * sx + sy * sy + sz * sz);
    float inv = 1.0f / ang;
    float ux = rx * inv, uy = ry * inv, uz = rz * inv;
    float c = cosf(ang), s = sinf(ang), omc = 1.0f - c;
    float K[3][3] = {{0.0f, -uz, uy}, {uz, 0.0f, -ux}, {-uy, ux, 0.0f}};
#pragma unroll
    for (int m = 0; m < 3; ++m)
#pragma unroll
      for (int n = 0; n < 3; ++n) {
        float k2 = 0.0f;
#pragma unroll
        for (int q = 0; q < 3; ++q) k2 += K[m][q] * K[q][n];
        R[j][m][n] = ((m == n) ? 1.0f : 0.0f) + s * K[m][n] + omc * k2;
      }
  }
  {
    float pf[36];
#pragma unroll
    for (int j = 1; j < 5; ++j)
#pragma unroll
      for (int m = 0; m < 3; ++m)
#pragma unroll
        for (int n = 0; n < 3; ++n)
          pf[(j - 1) * 9 + m * 3 + n] = R[j][m][n] - ((m == n) ? 1.0f : 0.0f);
    uint* bbu = (uint*)bb + (size_t)b * 96;
    int rr = b & 7;
#pragma unroll
    for (int q = 0; q < 18; ++q) {
      int cp = 75 + q;
      int kb = cp >> 2, e = cp & 3;
      bbu[((kb ^ rr) << 2) + e] = (uint)f2bf(pf[2 * q]) | ((uint)f2bf(pf[2 * q + 1]) << 16);
    }
  }
  float Jt[5][3];
#pragma unroll
  for (int j = 0; j < 5; ++j)
#pragma unroll
    for (int k = 0; k < 3; ++k) Jt[j][k] = JtL[g][j * 3 + k];
  const int par[5] = {0, 0, 1, 1, 1};
  float rel[5][3];
#pragma unroll
  for (int k = 0; k < 3; ++k) rel[0][k] = Jt[0][k];
#pragma unroll
  for (int j = 1; j < 5; ++j)
#pragma unroll
    for (int k = 0; k < 3; ++k) rel[j][k] = Jt[j][k] - Jt[par[j]][k];
  float Rg[5][3][3], tg[5][3];
#pragma unroll
  for (int m = 0; m < 3; ++m) {
#pragma unroll
    for (int n = 0; n < 3; ++n) Rg[0][m][n] = R[0][m][n];
    tg[0][m] = rel[0][m];
  }
#pragma unroll
  for (int j = 1; j < 5; ++j) {
    int p = par[j];
#pragma unroll
    for (int m = 0; m < 3; ++m) {
      float t2 = tg[p][m];
#pragma unroll
      for (int n = 0; n < 3; ++n) {
        float s = 0.0f;
#pragma unroll
        for (int q = 0; q < 3; ++q) s = fmaf(Rg[p][m][q], R[j][q][n], s);
        Rg[j][m][n] = s;
        t2 = fmaf(Rg[p][m][n], rel[j][n], t2);
      }
      tg[j][m] = t2;
    }
  }
#pragma unroll
  for (int j = 0; j < 5; ++j)
#pragma unroll
    for (int k = 0; k < 3; ++k)
      out[(size_t)B_N * V_N * 3 + ((size_t)b * 5 + j) * 3 + k] = tg[j][k];
  float Af[5][12];
#pragma unroll
  for (int j = 0; j < 5; ++j)
#pragma unroll
    for (int m = 0; m < 3; ++m) {
      float tj = 0.0f;
#pragma unroll
      for (int n = 0; n < 3; ++n) {
        Af[j][m * 4 + n] = Rg[j][m][n];
        tj = fmaf(Rg[j][m][n], Jt[j][n], tj);
      }
      Af[j][m * 4 + 3] = tg[j][m] - tj;
    }
  float* Ab = A + (size_t)b * 64;
#pragma unroll
  for (int q = 0; q < 12; ++q) Ab[q] = Af[0][q];
#pragma unroll
  for (int j = 1; j < 5; ++j)
#pragma unroll
    for (int q = 0; q < 12; ++q) Ab[j * 12 + q] = Af[j][q] - Af[0][q];
}

// ================= L3: MFMA GEMM + fused skinning (R14-proven) =================
// grid (32 batch-tiles FAST, 314 vertex-tiles). Pre-swizzled global data; linear async
// staging via global_load_lds width=16 (24 x 1KB chunks/tile; wave w -> chunks 3w..3w+2).
__global__ __launch_bounds__(512, 6) void k_main(const ushort* __restrict__ basis,
                                                 const ushort* __restrict__ bb,
                                                 const float* __restrict__ Amat,
                                                 const float* __restrict__ lw,
                                                 const float* __restrict__ vtemp,
                                                 float* __restrict__ out) {
  __shared__ alignas(16) ushort AL[64 * 192];
  __shared__ alignas(16) ushort BL[64 * 192];
  float* AmL = (float*)AL;
  int t = threadIdx.x;
  int bx = blockIdx.y;
  int by = blockIdx.x;
  int b0 = by * 64;
  int lane = t & 63;
  int w = __builtin_amdgcn_readfirstlane(t >> 6);
  {
    const char* gA = (const char*)(basis + (size_t)bx * 64 * 192);
    const char* gB = (const char*)(bb + (size_t)b0 * 192);
#pragma unroll
    for (int i = 0; i < 3; ++i) {
      int chunk = w * 3 + i;
      int off = chunk * 1024 + lane * 16;
      __builtin_amdgcn_global_load_lds(
          (const __attribute__((address_space(1))) uint*)(gA + off),
          (__attribute__((address_space(3))) uint*)((char*)&AL[0] + chunk * 1024), 16, 0, 0);
      __builtin_amdgcn_global_load_lds(
          (const __attribute__((address_space(1))) uint*)(gB + off),
          (__attribute__((address_space(3))) uint*)((char*)&BL[0] + chunk * 1024), 16, 0, 0);
    }
  }
  __syncthreads();
  int wm = w >> 1, wn = w & 1;
  int lm = lane & 15, g = lane >> 4;
  f32x4 acc0 = {0.f, 0.f, 0.f, 0.f}, acc1 = {0.f, 0.f, 0.f, 0.f};
  const int ar = wm * 16 + lm;
  const int br0 = wn * 32 + lm;
  const int br1 = wn * 32 + 16 + lm;
#pragma unroll
  for (int ks = 0; ks < 6; ++ks) {
    int kb = ks * 4 + g;
    short8 af = *(const short8*)(&AL[(ar * 24 + (kb ^ (ar & 7))) * 8]);
    short8 bf0 = *(const short8*)(&BL[(br0 * 24 + (kb ^ (br0 & 7))) * 8]);
    short8 bf1 = *(const short8*)(&BL[(br1 * 24 + (kb ^ (br1 & 7))) * 8]);
    acc0 = __builtin_amdgcn_mfma_f32_16x16x32_bf16(af, bf0, acc0, 0, 0, 0);
    acc1 = __builtin_amdgcn_mfma_f32_16x16x32_bf16(af, bf1, acc1, 0, 0, 0);
  }
  int v = bx * 16 + wm * 4 + g;
  bool valid = v < V_N;
  int vv = valid ? v : 0;
  float wv[4];
#pragma unroll
  for (int j = 0; j < 4; ++j) wv[j] = lw[(size_t)vv * 5 + 1 + j];
  float vt0 = vtemp[(size_t)vv * 3 + 0];
  float vt1 = vtemp[(size_t)vv * 3 + 1];
  float vt2 = vtemp[(size_t)vv * 3 + 2];
  __syncthreads();
#pragma unroll
  for (int i = 0; i < 2; ++i) {
    int c = t + i * 512;
    int r = c / 16, q = (c % 16) * 4;
    *(f32x4*)(&AmL[r * 68 + q]) = *(const f32x4*)(&Amat[((size_t)(b0 + r)) * 64 + q]);
  }
  __syncthreads();
#pragma unroll
  for (int ni = 0; ni < 2; ++ni) {
    f32x4 p = ni ? acc1 : acc0;
    int bl = wn * 32 + ni * 16 + lm;
    const float* Ar = &AmL[bl * 68];
    f32x4 T0 = *(const f32x4*)(Ar + 0);
    f32x4 T1 = *(const f32x4*)(Ar + 4);
    f32x4 T2 = *(const f32x4*)(Ar + 8);
#pragma unroll
    for (int j = 1; j < 5; ++j) {
      f32x4 d0 = *(const f32x4*)(Ar + j * 12 + 0);
      f32x4 d1 = *(const f32x4*)(Ar + j * 12 + 4);
      f32x4 d2 = *(const f32x4*)(Ar + j * 12 + 8);
      float wjv = wv[j - 1];
#pragma unroll
      for (int c = 0; c < 4; ++c) {
        T0[c] = fmaf(wjv, d0[c], T0[c]);
        T1[c] = fmaf(wjv, d1[c], T1[c]);
        T2[c] = fmaf(wjv, d2[c], T2[c]);
      }
    }
    float x = p[0] + vt0, y = p[1] + vt1, z = p[2] + vt2;
    float ox = fmaf(T0[0], x, fmaf(T0[1], y, fmaf(T0[2], z, T0[3])));
    float oy = fmaf(T1[0], x, fmaf(T1[1], y, fmaf(T1[2], z, T1[3])));
    float oz = fmaf(T2[0], x, fmaf(T2[1], y, fmaf(T2[2], z, T2[3])));
    if (valid) {
      size_t o = ((size_t)(b0 + bl)) * V3_N + (size_t)v * 3;
      out[o + 0] = ox;
      out[o + 1] = oy;
      out[o + 2] = oz;
    }
  }
}

extern "C" void kernel_launch(void* const* d_in, const int* in_sizes, int n_in,
                              void* d_out, int out_size, void* d_ws, size_t ws_size,
                              hipStream_t stream) {
  const float* shp = (const float*)d_in[0];
  const float* expr = (const float*)d_in[1];
  const float* pose = (const float*)d_in[2];
  const float* vtemp = (const float*)d_in[3];
  const float* sdirs = (const float*)d_in[4];
  const float* pdirs = (const float*)d_in[5];
  const float* Jr = (const float*)d_in[6];
  const float* lw = (const float*)d_in[7];
  float* out = (float*)d_out;
  float* wsf = (float*)d_ws;

  const size_t OFF_SJ = 358400;
  const size_t OFF_A = 786688;
  const size_t OFF_BB = 917760;
  const size_t OFF_BASIS = 1114368;
  float* SJ = wsf + OFF_SJ;
  float* A = wsf + OFF_A;
  ushort* bb = (ushort*)(wsf + OFF_BB);
  ushort* basis = (ushort*)(wsf + OFF_BASIS);

  hipLaunchKernelGGL(k_zero, dim3(9), dim3(256), 0, stream, SJ);
  hipLaunchKernelGGL(k_pre, dim3(314 + NSJB + 768), dim3(256), 0, stream,
                     sdirs, pdirs, vtemp, Jr, shp, expr, basis, SJ, bb);
  hipLaunchKernelGGL(k_jpose, dim3(128), dim3(256), 0, stream,
                     shp, expr, SJ, pose, bb, A, out);
  hipLaunchKernelGGL(k_main, dim3(32, 314), dim3(512), 0, stream,
                     basis, bb, A, lw, vtemp, out);
}